// Round 10
// baseline (271.635 us; speedup 1.0000x reference)
//
#include <hip/hip_runtime.h>
#include <math.h>

// Problem constants
#define D 64
#define HWD 4096          // 64*64
#define NVEC 131072       // 32*64*64
#define K 1024

// d_out layout (float element offsets: loss, out, perplexity, encodings, inputs)
// NOTE: O_ENC % 4 == 2 and O_INP % 4 == 2 -> 16B-aligned chunks sit at
// column offsets == 2 (mod 4).
#define O_LOSS 0
#define O_OUT  1
#define O_PERP 8388609ULL
#define O_ENC  8388610ULL
#define O_INP  142606338ULL   // 8388610 + 134217728

// d_ws layout (bytes)
#define WS_CBH   0          // K*D fp16 B-fragment-packed (131072 B)
#define WS_CBL   131072     // K*D fp16 lo part           (131072 B)
#define WS_C2    262144     // 1024 float                 (4096 B)
#define WS_HIST  266240     // 1024 int                   (4096 B)
#define WS_LPART 270336     // 4096 float                 (16384 B)
#define WS_IDX   286720     // 131072 ushort              (262144 B)

typedef _Float16 half8 __attribute__((ext_vector_type(8)));
typedef float    f32x16 __attribute__((ext_vector_type(16)));
typedef float    f32x4  __attribute__((ext_vector_type(4)));
typedef float    f32x2  __attribute__((ext_vector_type(2)));

// ---------------------------------------------------------------------------
// Fused prep: blocks 0-31 pack codebook into MFMA B-fragment layout (fp16
// hi/lo); blocks 32-35 compute ||c||^2 (fp32 exact).
__global__ __launch_bounds__(256) void prep_kernel(const float* __restrict__ cb,
                                                   _Float16* __restrict__ cbh,
                                                   _Float16* __restrict__ cbl,
                                                   float* __restrict__ c2) {
    if (blockIdx.x < 32) {
        int u  = blockIdx.x * 256 + threadIdx.x;   // 8192 units
        int l  = u & 63;
        int s  = (u >> 6) & 3;
        int kt = u >> 8;
        int k  = kt * 32 + (l & 31);
        int d0 = s * 16 + (l >> 5) * 8;
        const float* src = cb + k * D + d0;
        half8 h, lo;
        #pragma unroll
        for (int i = 0; i < 8; ++i) {
            float v = src[i];
            _Float16 hh = (_Float16)v;
            h[i]  = hh;
            lo[i] = (_Float16)(v - (float)hh);
        }
        reinterpret_cast<half8*>(cbh)[u] = h;
        reinterpret_cast<half8*>(cbl)[u] = lo;
    } else {
        int k = (blockIdx.x - 32) * 256 + threadIdx.x;
        const float4* row = reinterpret_cast<const float4*>(cb + k * D);
        float s = 0.f;
        #pragma unroll
        for (int q = 0; q < 16; ++q) {
            float4 c = row[q];
            s = fmaf(c.x, c.x, s); s = fmaf(c.y, c.y, s);
            s = fmaf(c.z, c.z, s); s = fmaf(c.w, c.w, s);
        }
        c2[k] = s;
    }
}

// ---------------------------------------------------------------------------
// Fused main, 32 rows per block (4096 blocks), low register pressure:
// per wave ~135 VGPR -> 3 blocks/CU (12 waves) for latency hiding and
// block-level store/compute phase skew.
//   Phase 0 : x load (each wave: its g-half of all 32 rows), inputs write
//             (wave w = d-chunk s=w), sx2
//   Phase 1 : MFMA argmin, 4 waves partition K (8 kt-tiles each), one
//             32x32 m-tile, fp16 hi/lo (3 products)
//   Phase 2 : cross-wave argmin, idx, hist, loss partial
//   Phase 3 : one-hot encodings (zeros+one fold), quantized NCHW
__global__ __launch_bounds__(256, 3) void vq_fused(
    const float* __restrict__ x, const float* __restrict__ cb,
    const _Float16* __restrict__ cbh, const _Float16* __restrict__ cbl,
    const float* __restrict__ c2, float* __restrict__ out,
    unsigned short* __restrict__ idxg,
    int* __restrict__ hist, float* __restrict__ lossPart)
{
    __shared__ float    sb[4][32];
    __shared__ unsigned sk[4][32];
    __shared__ float    ssx[32];
    __shared__ unsigned skf[32];

    const int lane = threadIdx.x & 63;
    const int wid  = threadIdx.x >> 6;
    const int col  = lane & 31;
    const int g    = lane >> 5;
    const int n0   = blockIdx.x * 32;
    const int b    = n0 >> 12;
    const int hw0  = n0 & 4095;
    const size_t bbase = (size_t)b << 18;   // b * D * HWD

    // ---- Phase 0: x loads. Lane (col,g) holds row n0+col, dims
    // d = s*16 + g*8 + i  (matches A-fragment layout of 32x32x16).
    float xv[4][8];
    {
        const float* xp = x + bbase + (hw0 + col);
        #pragma unroll
        for (int s = 0; s < 4; ++s)
            #pragma unroll
            for (int i = 0; i < 8; ++i)
                xv[s][i] = xp[(size_t)(s * 16 + g * 8 + i) << 12];
    }

    // ---- Phase 0b: inputs (NHWC). Wave w writes d-chunk s==w of all rows.
    // Abs offset == 2 (mod 4): f32x2 / aligned f32x4 / f32x2.
    #pragma unroll
    for (int s = 0; s < 4; ++s) {
        if (s == wid) {
            float* ip = out + O_INP + (size_t)(n0 + col) * 64 + s * 16 + g * 8;
            f32x2 h2 = {xv[s][0], xv[s][1]};
            f32x4 b4 = {xv[s][2], xv[s][3], xv[s][4], xv[s][5]};
            f32x2 t2 = {xv[s][6], xv[s][7]};
            __builtin_nontemporal_store(h2, reinterpret_cast<f32x2*>(ip));
            __builtin_nontemporal_store(b4, reinterpret_cast<f32x4*>(ip + 2));
            __builtin_nontemporal_store(t2, reinterpret_cast<f32x2*>(ip + 6));
        }
    }

    // sx2 per row (combine the two g-halves)
    {
        float sp = 0.f;
        #pragma unroll
        for (int s = 0; s < 4; ++s)
            #pragma unroll
            for (int i = 0; i < 8; ++i)
                sp = fmaf(xv[s][i], xv[s][i], sp);
        sp += __shfl_xor(sp, 32, 64);
        if (wid == 0 && g == 0) ssx[col] = sp;
    }

    // Convert to fp16 hi/lo A-fragments
    half8 ah[4], al[4];
    #pragma unroll
    for (int s = 0; s < 4; ++s)
        #pragma unroll
        for (int i = 0; i < 8; ++i) {
            _Float16 h = (_Float16)xv[s][i];
            ah[s][i] = h;
            al[s][i] = (_Float16)(xv[s][i] - (float)h);
        }

    // ---- Phase 1: MFMA argmin. score = ||c||^2 - 2 x.c
    float    best[16];
    unsigned kbest[16];
    #pragma unroll
    for (int r = 0; r < 16; ++r) { best[r] = 3.4e38f; kbest[r] = 0u; }

    const half8* Bh = reinterpret_cast<const half8*>(cbh);
    const half8* Bl = reinterpret_cast<const half8*>(cbl);

    for (int j = 0; j < 8; ++j) {
        int kt = wid * 8 + j;                  // this wave's 32-code tile
        half8 bh[4], bl_[4];
        #pragma unroll
        for (int s = 0; s < 4; ++s) {
            bh[s]  = Bh[(kt * 4 + s) * 64 + lane];   // coalesced, L2-resident
            bl_[s] = Bl[(kt * 4 + s) * 64 + lane];
        }
        float    c2v  = c2[kt * 32 + col];
        unsigned kcur = (unsigned)(kt * 32 + col);

        f32x16 a0;
        #pragma unroll
        for (int r = 0; r < 16; ++r) a0[r] = 0.f;

        #pragma unroll
        for (int s = 0; s < 4; ++s) {
            a0 = __builtin_amdgcn_mfma_f32_32x32x16_f16(ah[s], bh[s],  a0, 0, 0, 0);
            a0 = __builtin_amdgcn_mfma_f32_32x32x16_f16(al[s], bh[s],  a0, 0, 0, 0);
            a0 = __builtin_amdgcn_mfma_f32_32x32x16_f16(ah[s], bl_[s], a0, 0, 0, 0);
        }

        #pragma unroll
        for (int r = 0; r < 16; ++r) {
            float s0 = fmaf(-2.0f, a0[r], c2v);
            if (s0 < best[r]) { best[r] = s0; kbest[r] = kcur; }
        }
    }

    // Per-wave cross-lane argmin over the 32 cols
    #pragma unroll
    for (int r = 0; r < 16; ++r) {
        float bv = best[r]; unsigned kv = kbest[r];
        #pragma unroll
        for (int mask = 1; mask <= 16; mask <<= 1) {
            float    ob = __shfl_xor(bv, mask);
            unsigned ok = (unsigned)__shfl_xor((int)kv, mask);
            if (ob < bv || (ob == bv && ok < kv)) { bv = ob; kv = ok; }
        }
        if (col == 0) {
            int row = (r & 3) + 8 * (r >> 2) + 4 * g;   // C layout (m74/m101)
            sb[wid][row] = bv;
            sk[wid][row] = kv;
        }
    }
    __syncthreads();

    // ---- Phase 2: cross-wave combine, idx, loss partial, histogram
    if (threadIdx.x < 32) {
        int t = threadIdx.x;
        float bv = sb[0][t]; unsigned kv = sk[0][t];
        #pragma unroll
        for (int w = 1; w < 4; ++w) {
            float ob = sb[w][t];
            if (ob < bv) { bv = ob; kv = sk[w][t]; }
        }
        skf[t] = kv;
        idxg[n0 + t] = (unsigned short)kv;
        atomicAdd(&hist[kv], 1);
        float lp = bv + ssx[t];                 // ||c-x||^2 = score + ||x||^2
        #pragma unroll
        for (int mask = 1; mask <= 16; mask <<= 1) lp += __shfl_xor(lp, mask);
        if (t == 0) lossPart[blockIdx.x] = lp;
    }
    __syncthreads();

    // ---- Phase 3a: one-hot encodings, zeros+one folded, 32 rows x 4KB.
    {
        unsigned kvreg = (unsigned)skf[col];    // lane l holds skf[l&31]
        const int t  = threadIdx.x;
        const int c0 = 2 + 4 * t;
        float* rp = out + O_ENC + (size_t)n0 * K;
        #pragma unroll
        for (int r = 0; r < 32; ++r) {
            int skr = __builtin_amdgcn_readlane((int)kvreg, r);
            if (t < 255) {
                f32x4 v = {(float)(c0 == skr), (float)(c0 + 1 == skr),
                           (float)(c0 + 2 == skr), (float)(c0 + 3 == skr)};
                __builtin_nontemporal_store(v, reinterpret_cast<f32x4*>(rp + c0));
            } else {
                f32x2 h2 = {(float)(0 == skr), (float)(1 == skr)};
                f32x2 t2 = {(float)(1022 == skr), (float)(1023 == skr)};
                __builtin_nontemporal_store(h2, reinterpret_cast<f32x2*>(rp));
                __builtin_nontemporal_store(t2, reinterpret_cast<f32x2*>(rp + 1022));
            }
            rp += K;
        }
    }

    // ---- Phase 3b: quantized NCHW. lane = row + 32*h; wave w + half h ->
    // channels w*16 + h*8 + [0,8).
    {
        unsigned kr = skf[col];
        const float* crow = cb + (size_t)kr * D;
        float* ob = out + O_OUT + bbase + hw0 + col;
        #pragma unroll
        for (int c8 = 0; c8 < 8; ++c8) {
            int c = wid * 16 + g * 8 + c8;
            __builtin_nontemporal_store(crow[c], ob + ((size_t)c << 12));
        }
    }
}

// ---------------------------------------------------------------------------
// Scalars: perplexity from histogram, loss from 4096 partials
__global__ __launch_bounds__(1024) void final_kernel(
    const int* __restrict__ hist, const float* __restrict__ lossPart,
    float* __restrict__ out)
{
    __shared__ float red[1024];
    int t = threadIdx.x;

    float p = (float)hist[t] * (1.0f / (float)NVEC);
    red[t] = p * logf(p + 1e-10f);
    __syncthreads();
    for (int s = 512; s > 0; s >>= 1) {
        if (t < s) red[t] += red[t + s];
        __syncthreads();
    }
    float perp = expf(-red[0]);
    __syncthreads();

    red[t] = (lossPart[t] + lossPart[t + 1024])
           + (lossPart[t + 2048] + lossPart[t + 3072]);
    __syncthreads();
    for (int s = 512; s > 0; s >>= 1) {
        if (t < s) red[t] += red[t + s];
        __syncthreads();
    }
    if (t == 0) {
        out[O_PERP] = perp;
        out[O_LOSS] = 0.25f * red[0] / 8388608.0f;
    }
}

// ---------------------------------------------------------------------------
extern "C" void kernel_launch(void* const* d_in, const int* in_sizes, int n_in,
                              void* d_out, int out_size, void* d_ws, size_t ws_size,
                              hipStream_t stream) {
    const float* x  = (const float*)d_in[0];
    const float* cb = (const float*)d_in[1];
    float* out = (float*)d_out;

    char* ws = (char*)d_ws;
    _Float16* cbh   = (_Float16*)(ws + WS_CBH);
    _Float16* cbl   = (_Float16*)(ws + WS_CBL);
    float*    c2    = (float*)(ws + WS_C2);
    int*      hist  = (int*)(ws + WS_HIST);
    float*    lpart = (float*)(ws + WS_LPART);
    unsigned short* idx = (unsigned short*)(ws + WS_IDX);

    (void)hipMemsetAsync(hist, 0, K * sizeof(int), stream);

    prep_kernel<<<36, 256, 0, stream>>>(cb, cbh, cbl, c2);
    vq_fused<<<NVEC / 32, 256, 0, stream>>>(x, cb, cbh, cbl, c2, out, idx, hist, lpart);
    final_kernel<<<1, 1024, 0, stream>>>(hist, lpart, out);
}